// Round 5
// baseline (677.082 us; speedup 1.0000x reference)
//
#include <hip/hip_runtime.h>

typedef unsigned short u16;
typedef __attribute__((ext_vector_type(8))) __bf16 bf16x8;
typedef __attribute__((ext_vector_type(4))) float f32x4;
typedef __attribute__((ext_vector_type(4))) unsigned short u16x4;
typedef __attribute__((ext_vector_type(8))) unsigned short u16x8;

#define GLOBAL_AS __attribute__((address_space(1)))
#define LDS_AS __attribute__((address_space(3)))

__device__ __forceinline__ void gload_lds16(const void* g, void* l) {
    __builtin_amdgcn_global_load_lds((const GLOBAL_AS void*)g, (LDS_AS void*)l, 16, 0, 0);
}

__device__ __forceinline__ u16 f2bf(float f) {
    union { float f; unsigned u; } x; x.f = f;
    unsigned r = x.u + 0x7FFFu + ((x.u >> 16) & 1u);
    return (u16)(r >> 16);
}
__device__ __forceinline__ float bf2f(u16 h) {
    union { unsigned u; float f; } x; x.u = ((unsigned)h) << 16;
    return x.f;
}
struct BfPair { u16 h, l; };
// fp32 -> (hi,lo) bf16 pair; hi+lo reproduces v to ~2^-17 relative.
__device__ __forceinline__ BfPair split2(float v) {
    BfPair p;
    p.h = f2bf(v);
    p.l = f2bf(v - bf2f(p.h));
    return p;
}

#define TM 128
#define TN 128
#define BK 64

// ---------------- elementwise f32 -> bf16 (rne, same rounding as f2bf).
__global__ __launch_bounds__(256) void conv_bf(
    const float* __restrict__ src, u16* __restrict__ dst, int n8)
{
    const int stride = gridDim.x * 256;
    for (int i = blockIdx.x * 256 + threadIdx.x; i < n8; i += stride) {
        const float* g = src + (size_t)i * 8;
        f32x4 v0 = *(const f32x4*)g;
        f32x4 v1 = *(const f32x4*)(g + 4);
        u16x8 w;
        #pragma unroll
        for (int e = 0; e < 4; ++e) { w[e] = f2bf(v0[e]); w[e + 4] = f2bf(v1[e]); }
        *(u16x8*)(dst + (size_t)i * 8) = w;
    }
}

// ---------------- 3x transpose + f32->bf16 (z selects tensor): D[i][j] = bf16(S[j][i]), 2048x2048.
__global__ __launch_bounds__(256) void transpose3(
    const float* __restrict__ s0, const float* __restrict__ s1, const float* __restrict__ s2,
    u16* __restrict__ d0, u16* __restrict__ d1, u16* __restrict__ d2)
{
    __shared__ float tile[64][65];
    const int z = blockIdx.z;
    const float* S = (z == 0) ? s0 : (z == 1) ? s1 : s2;
    u16* D = (z == 0) ? d0 : (z == 1) ? d1 : d2;
    const int x0 = blockIdx.x * 64;
    const int y0 = blockIdx.y * 64;
    const int t = threadIdx.x;
    const int rt = t >> 4;
    const int c4 = (t & 15) * 4;

    #pragma unroll
    for (int p = 0; p < 4; ++p) {
        const int r = p * 16 + rt;
        f32x4 v = *(const f32x4*)(S + (size_t)(y0 + r) * 2048 + x0 + c4);
        #pragma unroll
        for (int e = 0; e < 4; ++e) tile[r][c4 + e] = v[e];
    }
    __syncthreads();
    #pragma unroll
    for (int p = 0; p < 4; ++p) {
        const int a = p * 16 + rt;
        u16x4 w;
        #pragma unroll
        for (int e = 0; e < 4; ++e) w[e] = f2bf(tile[c4 + e][a]);
        *(u16x4*)(D + (size_t)(x0 + a) * 2048 + y0 + c4) = w;
    }
}

// ---------------- paired small GEMM 128x128 (R3 form; z=0: Gt split w/ alpha; z=1: Ut single).
__global__ __launch_bounds__(256) void gemm_pre2(
    const u16* __restrict__ A0, const u16* __restrict__ B0,
    u16* __restrict__ GH, u16* __restrict__ GL, float alpha0,
    const u16* __restrict__ A1, const u16* __restrict__ B1, u16* __restrict__ U1,
    int M, int N, int K)
{
    __shared__ u16 As[TM * BK];
    __shared__ u16 Bs[TN * BK];

    const int z = blockIdx.z;
    const u16* Ab = z ? A1 : A0;
    const u16* Bb = z ? B1 : B0;

    const int n0 = blockIdx.x * TN;
    const int m0 = blockIdx.y * TM;
    const int tid = threadIdx.x;
    const int lane = tid & 63;
    const int wave = tid >> 6;
    const int wm = (wave >> 1) * 64;
    const int wn = (wave & 1) * 64;
    const int quad = lane >> 4;
    const int lrow = lane & 15;

    f32x4 acc[4][4] = {};

    for (int k0 = 0; k0 < K; k0 += BK) {
        #pragma unroll
        for (int r = 0; r < 4; ++r) {
            const int wbase = r * 4096 + wave * 1024;
            const int o = wbase + lane * 16;
            const int row = o >> 7;
            const int ce = (o & 127) >> 1;
            gload_lds16(Ab + (size_t)(m0 + row) * K + k0 + ce, (char*)As + wbase);
            gload_lds16(Bb + (size_t)(n0 + row) * K + k0 + ce, (char*)Bs + wbase);
        }
        __syncthreads();

        #pragma unroll
        for (int kk = 0; kk < BK; kk += 32) {
            bf16x8 af[4], bfr[4];
            #pragma unroll
            for (int t = 0; t < 4; ++t) {
                af[t]  = *(const bf16x8*)&As[(wm + t * 16 + lrow) * BK + kk + quad * 8];
                bfr[t] = *(const bf16x8*)&Bs[(wn + t * 16 + lrow) * BK + kk + quad * 8];
            }
            #pragma unroll
            for (int ti = 0; ti < 4; ++ti)
                #pragma unroll
                for (int tj = 0; tj < 4; ++tj)
                    acc[ti][tj] = __builtin_amdgcn_mfma_f32_16x16x32_bf16(
                        af[ti], bfr[tj], acc[ti][tj], 0, 0, 0);
        }
        __syncthreads();
    }

    #pragma unroll
    for (int ti = 0; ti < 4; ++ti)
        #pragma unroll
        for (int tj = 0; tj < 4; ++tj) {
            const int nn = n0 + wn + tj * 16 + lrow;
            #pragma unroll
            for (int r2 = 0; r2 < 4; ++r2) {
                const int mm = m0 + wm + ti * 16 + quad * 4 + r2;
                if (z == 0) {
                    BfPair p = split2(acc[ti][tj][r2] * alpha0);
                    GH[(size_t)mm * N + nn] = p.h;
                    GL[(size_t)mm * N + nn] = p.l;
                } else {
                    U1[(size_t)mm * N + nn] = f2bf(acc[ti][tj][r2]);
                }
            }
        }
}

// ---------------- A-single x B-split GEMM (2-term): C = A @ (Bh+Bl)^T.
// OSPLIT: split-bf16 output; else fp32 output. Batched; strides in BYTES.
template <bool OSPLIT>
__global__ __launch_bounds__(256) void gemm_bs(
    const u16* __restrict__ A,
    const u16* __restrict__ Bh, const u16* __restrict__ Bl,
    void* __restrict__ C, void* __restrict__ C2,
    int M, int N, int K, size_t sAb, size_t sBb, size_t sCb)
{
    __shared__ u16 As[TM * BK];
    __shared__ u16 Bsh[TN * BK];
    __shared__ u16 Bsl[TN * BK];

    const int z = blockIdx.z;
    const u16* Ab  = (const u16*)((const char*)A + (size_t)z * sAb);
    const u16* Bhb = (const u16*)((const char*)Bh + (size_t)z * sBb);
    const u16* Blb = (const u16*)((const char*)Bl + (size_t)z * sBb);

    const int n0 = blockIdx.x * TN;
    const int m0 = blockIdx.y * TM;
    const int tid = threadIdx.x;
    const int lane = tid & 63;
    const int wave = tid >> 6;
    const int wm = (wave >> 1) * 64;
    const int wn = (wave & 1) * 64;
    const int quad = lane >> 4;
    const int lrow = lane & 15;

    f32x4 acc[4][4] = {};

    for (int k0 = 0; k0 < K; k0 += BK) {
        #pragma unroll
        for (int r = 0; r < 4; ++r) {
            const int wbase = r * 4096 + wave * 1024;
            const int o = wbase + lane * 16;
            const int row = o >> 7;
            const int ce = (o & 127) >> 1;
            const size_t ao = (size_t)(m0 + row) * K + k0 + ce;
            const size_t bo = (size_t)(n0 + row) * K + k0 + ce;
            gload_lds16(Ab + ao, (char*)As + wbase);
            gload_lds16(Bhb + bo, (char*)Bsh + wbase);
            gload_lds16(Blb + bo, (char*)Bsl + wbase);
        }
        __syncthreads();

        #pragma unroll
        for (int kk = 0; kk < BK; kk += 32) {
            bf16x8 af[4], bh[4], bl[4];
            #pragma unroll
            for (int t = 0; t < 4; ++t) {
                const int ra = (wm + t * 16 + lrow) * BK + kk + quad * 8;
                const int rb = (wn + t * 16 + lrow) * BK + kk + quad * 8;
                af[t] = *(const bf16x8*)&As[ra];
                bh[t] = *(const bf16x8*)&Bsh[rb];
                bl[t] = *(const bf16x8*)&Bsl[rb];
            }
            #pragma unroll
            for (int ti = 0; ti < 4; ++ti)
                #pragma unroll
                for (int tj = 0; tj < 4; ++tj) {
                    acc[ti][tj] = __builtin_amdgcn_mfma_f32_16x16x32_bf16(
                        af[ti], bl[tj], acc[ti][tj], 0, 0, 0);
                    acc[ti][tj] = __builtin_amdgcn_mfma_f32_16x16x32_bf16(
                        af[ti], bh[tj], acc[ti][tj], 0, 0, 0);
                }
        }
        __syncthreads();
    }

    if (OSPLIT) {
        u16* Chb = (u16*)((char*)C + (size_t)z * sCb);
        u16* Clb = (u16*)((char*)C2 + (size_t)z * sCb);
        #pragma unroll
        for (int ti = 0; ti < 4; ++ti)
            #pragma unroll
            for (int tj = 0; tj < 4; ++tj) {
                const int nn = n0 + wn + tj * 16 + lrow;
                #pragma unroll
                for (int r2 = 0; r2 < 4; ++r2) {
                    const int mm = m0 + wm + ti * 16 + quad * 4 + r2;
                    BfPair p = split2(acc[ti][tj][r2]);
                    Chb[(size_t)mm * N + nn] = p.h;
                    Clb[(size_t)mm * N + nn] = p.l;
                }
            }
    } else {
        float* Cb = (float*)((char*)C + (size_t)z * sCb);
        #pragma unroll
        for (int ti = 0; ti < 4; ++ti)
            #pragma unroll
            for (int tj = 0; tj < 4; ++tj) {
                const int nn = n0 + wn + tj * 16 + lrow;
                #pragma unroll
                for (int r2 = 0; r2 < 4; ++r2) {
                    const int mm = m0 + wm + ti * 16 + quad * 4 + r2;
                    Cb[(size_t)mm * N + nn] = acc[ti][tj][r2];
                }
            }
    }
}

// ---------------- deep-pipeline GEMM: BM=256 x BN=128, BK=64, 512 thr (8 waves 4Mx2N),
// TRIPLE-buffered LDS (144 KiB, 1 block/CU), counted vmcnt(12), st-swizzled LDS.
// C[m,n] = sum_k A[m,k]*B[n,k] with dual-pointer K: A = (k<halfKA ? A0 : A1) col k%halfKA
// (B likewise) -> supports split-operand via K-doubling and plain GEMM (X1=X0).
// Safety: tile t+3 staged into buf[t%3] AFTER the barrier ending tile t's reads
// (previous occupant fully consumed); consumption waits vmcnt(12) (2 tiles in flight)
// + barrier => per-wave and cross-wave load completion guaranteed. EPI: 0=f32, 2=bf16.
#define DBM 256
#define DBN 128
template <int EPI>
__global__ __launch_bounds__(512, 2) void gemm_dp(
    const u16* __restrict__ A0, const u16* __restrict__ A1, int halfKA, int ldA, size_t sAb,
    const u16* __restrict__ B0, const u16* __restrict__ B1, int halfKB, int ldB, size_t sBb,
    void* __restrict__ C, size_t sCb, int M, int N, int Ktot)
{
    __shared__ alignas(16) u16 As[3 * DBM * BK];   // 3 x 32 KiB
    __shared__ alignas(16) u16 Bs[3 * DBN * BK];   // 3 x 16 KiB

    const int z = blockIdx.z;
    const u16* A0b = (const u16*)((const char*)A0 + (size_t)z * sAb);
    const u16* A1b = (const u16*)((const char*)A1 + (size_t)z * sAb);
    const u16* B0b = (const u16*)((const char*)B0 + (size_t)z * sBb);
    const u16* B1b = (const u16*)((const char*)B1 + (size_t)z * sBb);

    const int n0 = blockIdx.x * DBN;
    const int m0 = blockIdx.y * DBM;
    const int tid = threadIdx.x;
    const int lane = tid & 63;
    const int wid = tid >> 6;
    const int wr = wid >> 1;          // 0..3  (M quarter: 64 rows)
    const int wc = wid & 1;           // 0..1  (N half: 64 cols)
    const int quad = lane >> 4;
    const int lrow = lane & 15;

    // Staging map: linear LDS offset o holds logical offset L = o ^ (((o>>9)&1)<<5)
    // (st-swizzle involution; bit9 = (row>>2)&1 since rows are 128 B).
    int arow[4], acol[4], brow[2], bcol[2];
    #pragma unroll
    for (int s = 0; s < 4; ++s) {
        const int o = s * 8192 + tid * 16;
        const int L = o ^ (((o >> 9) & 1) << 5);
        arow[s] = L >> 7; acol[s] = L & 127;
    }
    #pragma unroll
    for (int s = 0; s < 2; ++s) {
        const int o = s * 8192 + tid * 16;
        const int L = o ^ (((o >> 9) & 1) << 5);
        brow[s] = L >> 7; bcol[s] = L & 127;
    }
    const int ldst = wid * 1024;      // wave-uniform LDS dest base offset

    const int NT = Ktot / BK;

    auto STAGE = [&](int tt, int bufi) {
        const int k0 = tt * BK;
        const u16* Ap = (k0 < halfKA) ? A0b : A1b;
        const int ka = (k0 < halfKA) ? k0 : k0 - halfKA;
        const u16* Bp = (k0 < halfKB) ? B0b : B1b;
        const int kb = (k0 < halfKB) ? k0 : k0 - halfKB;
        char* ab = (char*)As + bufi * (DBM * BK * 2);
        char* bb = (char*)Bs + bufi * (DBN * BK * 2);
        #pragma unroll
        for (int s = 0; s < 4; ++s)
            gload_lds16((const char*)Ap + ((size_t)(m0 + arow[s]) * ldA + ka) * 2 + acol[s],
                        ab + s * 8192 + ldst);
        #pragma unroll
        for (int s = 0; s < 2; ++s)
            gload_lds16((const char*)Bp + ((size_t)(n0 + brow[s]) * ldB + kb) * 2 + bcol[s],
                        bb + s * 8192 + ldst);
    };

    f32x4 acc[4][4] = {};

    STAGE(0, 0); STAGE(1, 1); STAGE(2, 2);   // 18 loads in flight

    int cur = 0;
    for (int t = 0; t < NT; ++t) {
        // tile t's 6 loads are 3rd-newest stage -> vmcnt(12) retires them (per wave);
        // barrier makes it collective.
        asm volatile("s_waitcnt vmcnt(12)" ::: "memory");
        __builtin_amdgcn_s_barrier();
        __builtin_amdgcn_sched_barrier(0);

        const char* ab = (const char*)As + cur * (DBM * BK * 2);
        const char* bb = (const char*)Bs + cur * (DBN * BK * 2);
        #pragma unroll
        for (int kk = 0; kk < BK; kk += 32) {
            bf16x8 af[4], bfr[4];
            const int cbase = kk * 2 + quad * 16;
            #pragma unroll
            for (int f = 0; f < 4; ++f) {
                const int ra = wr * 64 + f * 16 + lrow;
                af[f] = *(const bf16x8*)(ab + ra * 128 + (cbase ^ (((ra >> 2) & 1) << 5)));
                const int rb = wc * 64 + f * 16 + lrow;
                bfr[f] = *(const bf16x8*)(bb + rb * 128 + (cbase ^ (((rb >> 2) & 1) << 5)));
            }
            #pragma unroll
            for (int ti = 0; ti < 4; ++ti)
                #pragma unroll
                for (int tj = 0; tj < 4; ++tj)
                    acc[ti][tj] = __builtin_amdgcn_mfma_f32_16x16x32_bf16(
                        af[ti], bfr[tj], acc[ti][tj], 0, 0, 0);
        }
        __builtin_amdgcn_sched_barrier(0);
        __builtin_amdgcn_s_barrier();     // all waves done reading tile t
        __builtin_amdgcn_sched_barrier(0);
        if (t + 3 < NT) STAGE(t + 3, cur);  // overwrite t's (dead) buffer
        cur = (cur == 2) ? 0 : cur + 1;
    }

    #pragma unroll
    for (int ti = 0; ti < 4; ++ti)
        #pragma unroll
        for (int tj = 0; tj < 4; ++tj) {
            const int nn = n0 + wc * 64 + tj * 16 + lrow;
            #pragma unroll
            for (int r2 = 0; r2 < 4; ++r2) {
                const int mm = m0 + wr * 64 + ti * 16 + quad * 4 + r2;
                if (EPI == 0) {
                    float* Cb = (float*)((char*)C + (size_t)z * sCb);
                    Cb[(size_t)mm * N + nn] = acc[ti][tj][r2];
                } else {
                    u16* Cb = (u16*)((char*)C + (size_t)z * sCb);
                    Cb[(size_t)mm * N + nn] = f2bf(acc[ti][tj][r2]);
                }
            }
        }
}

// Row softmax over Lh (8192 rows x 1024 fp32), diag (j == row%1024) -> -inf.
// Split-bf16 output.
__global__ __launch_bounds__(256) void softmax_split(
    const float* __restrict__ Lh, u16* __restrict__ Th, u16* __restrict__ Tl)
{
    const int lane = threadIdx.x & 63;
    const int wave = threadIdx.x >> 6;
    const size_t row = (size_t)blockIdx.x * 4 + wave;
    const int i = (int)(row & 1023);
    const float* src = Lh + row * 1024;
    const float NEG = -__builtin_inff();

    float v[16];
    float mx = NEG;
    #pragma unroll
    for (int cc = 0; cc < 4; ++cc) {
        f32x4 x = *(const f32x4*)(src + cc * 256 + lane * 4);
        #pragma unroll
        for (int e = 0; e < 4; ++e) {
            const int j = cc * 256 + lane * 4 + e;
            const float val = (j == i) ? NEG : x[e];
            v[cc * 4 + e] = val;
            mx = fmaxf(mx, val);
        }
    }
    #pragma unroll
    for (int off = 32; off > 0; off >>= 1) mx = fmaxf(mx, __shfl_xor(mx, off, 64));
    float s = 0.f;
    #pragma unroll
    for (int k = 0; k < 16; ++k) { v[k] = __expf(v[k] - mx); s += v[k]; }
    #pragma unroll
    for (int off = 32; off > 0; off >>= 1) s += __shfl_xor(s, off, 64);
    const float inv = 1.0f / s;

    #pragma unroll
    for (int cc = 0; cc < 4; ++cc) {
        u16x4 wh, wl;
        #pragma unroll
        for (int e = 0; e < 4; ++e) {
            BfPair p = split2(v[cc * 4 + e] * inv);
            wh[e] = p.h;
            wl[e] = p.l;
        }
        *(u16x4*)(Th + row * 1024 + cc * 256 + lane * 4) = wh;
        *(u16x4*)(Tl + row * 1024 + cc * 256 + lane * 4) = wl;
    }
}

// attn_f32[b][i][j] = (Th+Tl)[b][j][i]
__global__ __launch_bounds__(256) void transpose_attn_f32(
    const u16* __restrict__ Th, const u16* __restrict__ Tl, float* __restrict__ A)
{
    __shared__ float tile[64][65];
    const int bz = blockIdx.z;
    const int x0 = blockIdx.x * 64;
    const int y0 = blockIdx.y * 64;
    const size_t base = (size_t)bz * 1024 * 1024;
    float* dst = A + base;
    const int t = threadIdx.x;
    const int rt = t >> 4;
    const int c4 = (t & 15) * 4;

    #pragma unroll
    for (int p = 0; p < 4; ++p) {
        const int r = p * 16 + rt;
        const size_t off = base + (size_t)(y0 + r) * 1024 + x0 + c4;
        u16x4 vh = *(const u16x4*)(Th + off);
        u16x4 vl = *(const u16x4*)(Tl + off);
        #pragma unroll
        for (int e = 0; e < 4; ++e) tile[r][c4 + e] = bf2f(vh[e]) + bf2f(vl[e]);
    }
    __syncthreads();
    #pragma unroll
    for (int p = 0; p < 4; ++p) {
        const int a = p * 16 + rt;
        f32x4 w;
        #pragma unroll
        for (int e = 0; e < 4; ++e) w[e] = tile[c4 + e][a];
        *(f32x4*)(dst + (size_t)(x0 + a) * 1024 + y0 + c4) = w;
    }
}

extern "C" void kernel_launch(void* const* d_in, const int* in_sizes, int n_in,
                              void* d_out, int out_size, void* d_ws, size_t ws_size,
                              hipStream_t stream) {
    const float* y  = (const float*)d_in[0];   // (8,1024,2048) fp32
    const float* Wk = (const float*)d_in[1];   // (2048,2048)
    const float* Wq = (const float*)d_in[2];
    const float* Wv = (const float*)d_in[3];
    const float* Wo = (const float*)d_in[4];

    const int b = 8, n = 1024, d = 2048;
    const int MB = b * n;                 // 8192
    const size_t MiB = 1024 * 1024;

    // ===== Algebra:
    //   Gt[d',dd] = 0.1 * sum_e Wk[e,d']*Wq[e,dd]
    //   Zc[i,d']  = sum_dd yB[i,dd]*Gt[d',dd]               (2-term, Gt split)
    //   Lt[b,m,n] = sum_d' y_b[m,d']*Zc[b,n,d'] = K_m.Q_n   (2-term, Zc split)
    //   Ut[e,dd]  = sum_d Wo[e,d]*Wv[d,dd]
    //   VOt[b,e,j]= sum_dd Ut[e,dd]*y_b[j,dd]               (gemm_dp, plain)
    //   out[b,i,e]= sum_j (Th+Tl)[b,i,j]*VOt[b,e,j]         (gemm_dp, A split via K-doubling)
    // ===== Buffer liveness (sequential stream; no same-kernel in/out alias):
    // ws (128 MiB):
    //   [0,32)   yB ; [32,40) WkT |[40,48) WqT |[48,56) WvT |[56,64) WoB (dead after pre2)
    //   [64,72)  GtH |[72,80) GtL (dead after Zc) ; [80,88) UtB (live till VOt)
    //   [32,64)  ZcH (over W's) ; [88,120) ZcL           (dead after Lt)
    //   [32,48)  Th / [48,64) Tl (over ZcH) ; [88,120) VOt (over ZcL)
    // d_out (96 MiB): [0,32) Lh (dead after softmax) -> outF [0,64) ; [64,96) attF
    char* ws = (char*)d_ws;
    u16* yB  = (u16*)(ws);
    u16* WkT = (u16*)(ws + 32 * MiB);
    u16* WqT = (u16*)(ws + 40 * MiB);
    u16* WvT = (u16*)(ws + 48 * MiB);
    u16* WoB = (u16*)(ws + 56 * MiB);
    u16* GtH = (u16*)(ws + 64 * MiB);
    u16* GtL = (u16*)(ws + 72 * MiB);
    u16* UtB = (u16*)(ws + 80 * MiB);
    u16* ZcH = (u16*)(ws + 32 * MiB);   // over WkT..WoB (dead)
    u16* ZcL = (u16*)(ws + 88 * MiB);
    u16* Th  = (u16*)(ws + 32 * MiB);   // over ZcH (dead after Lt)
    u16* Tl  = (u16*)(ws + 48 * MiB);
    u16* VOt = (u16*)(ws + 88 * MiB);   // over ZcL (dead after Lt)

    float* outF = (float*)d_out;                       // [0,64) final
    float* attF = outF + (size_t)MB * d;               // [64,96) final
    float* Lh   = (float*)d_out;                       // [0,32), dead before outF

    dim3 blk(256);
    dim3 blk5(512);
    // 1) y -> bf16; Wo -> bf16; Wk/Wq/Wv -> transposed bf16
    conv_bf<<<dim3(2048), blk, 0, stream>>>(y,  yB,  (MB * d) / 8);
    conv_bf<<<dim3(512),  blk, 0, stream>>>(Wo, WoB, (d * d) / 8);
    transpose3<<<dim3(32, 32, 3), blk, 0, stream>>>(Wk, Wq, Wv, WkT, WqT, WvT);
    // 2) z=0: Gt = 0.1*WkT@WqT^T -> split; z=1: Ut = WoB@WvT^T -> single
    gemm_pre2<<<dim3(d / TN, d / TM, 2), blk, 0, stream>>>(
        WkT, WqT, GtH, GtL, 0.1f, WoB, WvT, UtB, d, d, d);
    // 3) Zc = yB @ Gt^T (2-term) -> split   (ZcH over dead W region)
    gemm_bs<true><<<dim3(d / TN, MB / TM, 1), blk, 0, stream>>>(
        yB, GtH, GtL, ZcH, ZcL, MB, d, d, 0, 0, 0);
    // 4) Lt[b,m,n] = sum_d' y_b[m,d']*Zc_b[n,d'] (2-term) -> fp32
    gemm_bs<false><<<dim3(n / TN, n / TM, b), blk, 0, stream>>>(
        yB, ZcH, ZcL, Lh, nullptr, n, n, d,
        (size_t)n * d * 2, (size_t)n * d * 2, (size_t)n * n * 4);
    // 5) T = row_softmax(Lt, diag) -> split (Th/Tl over ZcH; dead)
    softmax_split<<<dim3(MB / 4), blk, 0, stream>>>(Lh, Th, Tl);
    // 6) attn = (Th+Tl)^T as fp32 (Lh dead after)
    transpose_attn_f32<<<dim3(16, 16, b), blk, 0, stream>>>(Th, Tl, attF);
    // 7) VOt[b,e,j] = sum_dd Ut[e,dd]*y_b[j,dd] -> bf16 (deep-pipeline; over ZcL; dead)
    gemm_dp<2><<<dim3(n / DBN, d / DBM, b), blk5, 0, stream>>>(
        UtB, UtB, d, d, 0,
        yB, yB, d, d, (size_t)n * d * 2,
        VOt, (size_t)d * n * 2, d, n, d);
    // 8) out[b,i,e] = sum_j (Th+Tl)[b,i,j]*VOt[b,e,j] -> fp32 (deep-pipeline,
    //    A = Th then Tl via K-doubling, B wraps; Lh dead)
    gemm_dp<0><<<dim3(d / DBN, n / DBM, b), blk5, 0, stream>>>(
        Th, Tl, n, n, (size_t)n * n * 2,
        VOt, VOt, n, n, (size_t)d * n * 2,
        outF, (size_t)n * d * 4, n, d, 2 * n);
}

// Round 6
// 643.791 us; speedup vs baseline: 1.0517x; 1.0517x over previous
//
#include <hip/hip_runtime.h>

typedef unsigned short u16;
typedef __attribute__((ext_vector_type(8))) __bf16 bf16x8;
typedef __attribute__((ext_vector_type(4))) float f32x4;
typedef __attribute__((ext_vector_type(4))) unsigned short u16x4;
typedef __attribute__((ext_vector_type(8))) unsigned short u16x8;

#define GLOBAL_AS __attribute__((address_space(1)))
#define LDS_AS __attribute__((address_space(3)))

__device__ __forceinline__ void gload_lds16(const void* g, void* l) {
    __builtin_amdgcn_global_load_lds((const GLOBAL_AS void*)g, (LDS_AS void*)l, 16, 0, 0);
}

__device__ __forceinline__ u16 f2bf(float f) {
    union { float f; unsigned u; } x; x.f = f;
    unsigned r = x.u + 0x7FFFu + ((x.u >> 16) & 1u);
    return (u16)(r >> 16);
}
__device__ __forceinline__ float bf2f(u16 h) {
    union { unsigned u; float f; } x; x.u = ((unsigned)h) << 16;
    return x.f;
}
struct BfPair { u16 h, l; };
// fp32 -> (hi,lo) bf16 pair; hi+lo reproduces v to ~2^-17 relative.
__device__ __forceinline__ BfPair split2(float v) {
    BfPair p;
    p.h = f2bf(v);
    p.l = f2bf(v - bf2f(p.h));
    return p;
}

#define TM 128
#define TN 128
#define BK 64

// ---------------- elementwise f32 -> bf16 (rne, same rounding as f2bf).
__global__ __launch_bounds__(256) void conv_bf(
    const float* __restrict__ src, u16* __restrict__ dst, int n8)
{
    const int stride = gridDim.x * 256;
    for (int i = blockIdx.x * 256 + threadIdx.x; i < n8; i += stride) {
        const float* g = src + (size_t)i * 8;
        f32x4 v0 = *(const f32x4*)g;
        f32x4 v1 = *(const f32x4*)(g + 4);
        u16x8 w;
        #pragma unroll
        for (int e = 0; e < 4; ++e) { w[e] = f2bf(v0[e]); w[e + 4] = f2bf(v1[e]); }
        *(u16x8*)(dst + (size_t)i * 8) = w;
    }
}

// ---------------- 3x transpose + f32->bf16 (z selects tensor): D[i][j] = bf16(S[j][i]), 2048x2048.
__global__ __launch_bounds__(256) void transpose3(
    const float* __restrict__ s0, const float* __restrict__ s1, const float* __restrict__ s2,
    u16* __restrict__ d0, u16* __restrict__ d1, u16* __restrict__ d2)
{
    __shared__ float tile[64][65];
    const int z = blockIdx.z;
    const float* S = (z == 0) ? s0 : (z == 1) ? s1 : s2;
    u16* D = (z == 0) ? d0 : (z == 1) ? d1 : d2;
    const int x0 = blockIdx.x * 64;
    const int y0 = blockIdx.y * 64;
    const int t = threadIdx.x;
    const int rt = t >> 4;
    const int c4 = (t & 15) * 4;

    #pragma unroll
    for (int p = 0; p < 4; ++p) {
        const int r = p * 16 + rt;
        f32x4 v = *(const f32x4*)(S + (size_t)(y0 + r) * 2048 + x0 + c4);
        #pragma unroll
        for (int e = 0; e < 4; ++e) tile[r][c4 + e] = v[e];
    }
    __syncthreads();
    #pragma unroll
    for (int p = 0; p < 4; ++p) {
        const int a = p * 16 + rt;
        u16x4 w;
        #pragma unroll
        for (int e = 0; e < 4; ++e) w[e] = f2bf(tile[c4 + e][a]);
        *(u16x4*)(D + (size_t)(x0 + a) * 2048 + y0 + c4) = w;
    }
}

// ---------------- merged pre GEMM: one block computes BOTH the Gt tile and the Ut
// tile at (m0,n0): 4 staged buffers, 64 MFMA per sync-pair (the density law: 64/sync
// ~ 875 TF vs 32/sync ~ 543). Gt = alpha0*A0@B0^T -> split; Ut = A1@B1^T -> single.
// All 2048^3; per-element accumulation order identical to the split launches.
__global__ __launch_bounds__(256, 2) void gemm_pre(
    const u16* __restrict__ A0, const u16* __restrict__ B0,
    u16* __restrict__ GH, u16* __restrict__ GL, float alpha0,
    const u16* __restrict__ A1, const u16* __restrict__ B1, u16* __restrict__ U1,
    int N, int K)
{
    __shared__ u16 As0[TM * BK];
    __shared__ u16 Bs0[TN * BK];
    __shared__ u16 As1[TM * BK];
    __shared__ u16 Bs1[TN * BK];

    const int n0 = blockIdx.x * TN;
    const int m0 = blockIdx.y * TM;
    const int tid = threadIdx.x;
    const int lane = tid & 63;
    const int wave = tid >> 6;
    const int wm = (wave >> 1) * 64;
    const int wn = (wave & 1) * 64;
    const int quad = lane >> 4;
    const int lrow = lane & 15;

    f32x4 acc0[4][4] = {};
    f32x4 acc1[4][4] = {};

    for (int k0 = 0; k0 < K; k0 += BK) {
        #pragma unroll
        for (int r = 0; r < 4; ++r) {
            const int wbase = r * 4096 + wave * 1024;
            const int o = wbase + lane * 16;
            const int row = o >> 7;
            const int ce = (o & 127) >> 1;
            const size_t ao = (size_t)(m0 + row) * K + k0 + ce;
            const size_t bo = (size_t)(n0 + row) * K + k0 + ce;
            gload_lds16(A0 + ao, (char*)As0 + wbase);
            gload_lds16(B0 + bo, (char*)Bs0 + wbase);
            gload_lds16(A1 + ao, (char*)As1 + wbase);
            gload_lds16(B1 + bo, (char*)Bs1 + wbase);
        }
        __syncthreads();

        #pragma unroll
        for (int kk = 0; kk < BK; kk += 32) {
            bf16x8 a0[4], b0[4], a1[4], b1[4];
            #pragma unroll
            for (int t = 0; t < 4; ++t) {
                const int ra = (wm + t * 16 + lrow) * BK + kk + quad * 8;
                const int rb = (wn + t * 16 + lrow) * BK + kk + quad * 8;
                a0[t] = *(const bf16x8*)&As0[ra];
                b0[t] = *(const bf16x8*)&Bs0[rb];
                a1[t] = *(const bf16x8*)&As1[ra];
                b1[t] = *(const bf16x8*)&Bs1[rb];
            }
            #pragma unroll
            for (int ti = 0; ti < 4; ++ti)
                #pragma unroll
                for (int tj = 0; tj < 4; ++tj) {
                    acc0[ti][tj] = __builtin_amdgcn_mfma_f32_16x16x32_bf16(
                        a0[ti], b0[tj], acc0[ti][tj], 0, 0, 0);
                    acc1[ti][tj] = __builtin_amdgcn_mfma_f32_16x16x32_bf16(
                        a1[ti], b1[tj], acc1[ti][tj], 0, 0, 0);
                }
        }
        __syncthreads();
    }

    #pragma unroll
    for (int ti = 0; ti < 4; ++ti)
        #pragma unroll
        for (int tj = 0; tj < 4; ++tj) {
            const int nn = n0 + wn + tj * 16 + lrow;
            #pragma unroll
            for (int r2 = 0; r2 < 4; ++r2) {
                const int mm = m0 + wm + ti * 16 + quad * 4 + r2;
                BfPair p = split2(acc0[ti][tj][r2] * alpha0);
                GH[(size_t)mm * N + nn] = p.h;
                GL[(size_t)mm * N + nn] = p.l;
                U1[(size_t)mm * N + nn] = f2bf(acc1[ti][tj][r2]);
            }
        }
}

// ---------------- A-single x B-split GEMM (2-term): C = A @ (Bh+Bl)^T.
// OSPLIT: split-bf16 output; else fp32 output. Batched; strides in BYTES.
template <bool OSPLIT>
__global__ __launch_bounds__(256) void gemm_bs(
    const u16* __restrict__ A,
    const u16* __restrict__ Bh, const u16* __restrict__ Bl,
    void* __restrict__ C, void* __restrict__ C2,
    int M, int N, int K, size_t sAb, size_t sBb, size_t sCb)
{
    __shared__ u16 As[TM * BK];
    __shared__ u16 Bsh[TN * BK];
    __shared__ u16 Bsl[TN * BK];

    const int z = blockIdx.z;
    const u16* Ab  = (const u16*)((const char*)A + (size_t)z * sAb);
    const u16* Bhb = (const u16*)((const char*)Bh + (size_t)z * sBb);
    const u16* Blb = (const u16*)((const char*)Bl + (size_t)z * sBb);

    const int n0 = blockIdx.x * TN;
    const int m0 = blockIdx.y * TM;
    const int tid = threadIdx.x;
    const int lane = tid & 63;
    const int wave = tid >> 6;
    const int wm = (wave >> 1) * 64;
    const int wn = (wave & 1) * 64;
    const int quad = lane >> 4;
    const int lrow = lane & 15;

    f32x4 acc[4][4] = {};

    for (int k0 = 0; k0 < K; k0 += BK) {
        #pragma unroll
        for (int r = 0; r < 4; ++r) {
            const int wbase = r * 4096 + wave * 1024;
            const int o = wbase + lane * 16;
            const int row = o >> 7;
            const int ce = (o & 127) >> 1;
            const size_t ao = (size_t)(m0 + row) * K + k0 + ce;
            const size_t bo = (size_t)(n0 + row) * K + k0 + ce;
            gload_lds16(Ab + ao, (char*)As + wbase);
            gload_lds16(Bhb + bo, (char*)Bsh + wbase);
            gload_lds16(Blb + bo, (char*)Bsl + wbase);
        }
        __syncthreads();

        #pragma unroll
        for (int kk = 0; kk < BK; kk += 32) {
            bf16x8 af[4], bh[4], bl[4];
            #pragma unroll
            for (int t = 0; t < 4; ++t) {
                const int ra = (wm + t * 16 + lrow) * BK + kk + quad * 8;
                const int rb = (wn + t * 16 + lrow) * BK + kk + quad * 8;
                af[t] = *(const bf16x8*)&As[ra];
                bh[t] = *(const bf16x8*)&Bsh[rb];
                bl[t] = *(const bf16x8*)&Bsl[rb];
            }
            #pragma unroll
            for (int ti = 0; ti < 4; ++ti)
                #pragma unroll
                for (int tj = 0; tj < 4; ++tj) {
                    acc[ti][tj] = __builtin_amdgcn_mfma_f32_16x16x32_bf16(
                        af[ti], bl[tj], acc[ti][tj], 0, 0, 0);
                    acc[ti][tj] = __builtin_amdgcn_mfma_f32_16x16x32_bf16(
                        af[ti], bh[tj], acc[ti][tj], 0, 0, 0);
                }
        }
        __syncthreads();
    }

    if (OSPLIT) {
        u16* Chb = (u16*)((char*)C + (size_t)z * sCb);
        u16* Clb = (u16*)((char*)C2 + (size_t)z * sCb);
        #pragma unroll
        for (int ti = 0; ti < 4; ++ti)
            #pragma unroll
            for (int tj = 0; tj < 4; ++tj) {
                const int nn = n0 + wn + tj * 16 + lrow;
                #pragma unroll
                for (int r2 = 0; r2 < 4; ++r2) {
                    const int mm = m0 + wm + ti * 16 + quad * 4 + r2;
                    BfPair p = split2(acc[ti][tj][r2]);
                    Chb[(size_t)mm * N + nn] = p.h;
                    Clb[(size_t)mm * N + nn] = p.l;
                }
            }
    } else {
        float* Cb = (float*)((char*)C + (size_t)z * sCb);
        #pragma unroll
        for (int ti = 0; ti < 4; ++ti)
            #pragma unroll
            for (int tj = 0; tj < 4; ++tj) {
                const int nn = n0 + wn + tj * 16 + lrow;
                #pragma unroll
                for (int r2 = 0; r2 < 4; ++r2) {
                    const int mm = m0 + wm + ti * 16 + quad * 4 + r2;
                    Cb[(size_t)mm * N + nn] = acc[ti][tj][r2];
                }
            }
    }
}

// ---------------- batch-paired 1-term GEMM for VOt: A (Ut) is batch-independent,
// so one block computes the same (m0,n0) tile for TWO batches sharing the staged
// A-tile: 3 staged buffers, 64 MFMA/sync (875-class density vs 543 for 32/sync).
// C_z[m,n] = sum_k A[m,k] * B_z[n,k] -> single-bf16. Strides in BYTES.
__global__ __launch_bounds__(256, 2) void gemm_vo(
    const u16* __restrict__ A, const u16* __restrict__ B,
    u16* __restrict__ C,
    int M, int N, int K, size_t sBb, size_t sCb)
{
    __shared__ u16 As[TM * BK];
    __shared__ u16 Bs0[TN * BK];
    __shared__ u16 Bs1[TN * BK];

    const int z0 = blockIdx.z * 2;
    const u16* B0b = (const u16*)((const char*)B + (size_t)z0 * sBb);
    const u16* B1b = (const u16*)((const char*)B + (size_t)(z0 + 1) * sBb);

    const int n0 = blockIdx.x * TN;
    const int m0 = blockIdx.y * TM;
    const int tid = threadIdx.x;
    const int lane = tid & 63;
    const int wave = tid >> 6;
    const int wm = (wave >> 1) * 64;
    const int wn = (wave & 1) * 64;
    const int quad = lane >> 4;
    const int lrow = lane & 15;

    f32x4 acc0[4][4] = {};
    f32x4 acc1[4][4] = {};

    for (int k0 = 0; k0 < K; k0 += BK) {
        #pragma unroll
        for (int r = 0; r < 4; ++r) {
            const int wbase = r * 4096 + wave * 1024;
            const int o = wbase + lane * 16;
            const int row = o >> 7;
            const int ce = (o & 127) >> 1;
            const size_t ao = (size_t)(m0 + row) * K + k0 + ce;
            const size_t bo = (size_t)(n0 + row) * K + k0 + ce;
            gload_lds16(A + ao, (char*)As + wbase);
            gload_lds16(B0b + bo, (char*)Bs0 + wbase);
            gload_lds16(B1b + bo, (char*)Bs1 + wbase);
        }
        __syncthreads();

        #pragma unroll
        for (int kk = 0; kk < BK; kk += 32) {
            bf16x8 af[4], b0[4], b1[4];
            #pragma unroll
            for (int t = 0; t < 4; ++t) {
                const int ra = (wm + t * 16 + lrow) * BK + kk + quad * 8;
                const int rb = (wn + t * 16 + lrow) * BK + kk + quad * 8;
                af[t] = *(const bf16x8*)&As[ra];
                b0[t] = *(const bf16x8*)&Bs0[rb];
                b1[t] = *(const bf16x8*)&Bs1[rb];
            }
            #pragma unroll
            for (int ti = 0; ti < 4; ++ti)
                #pragma unroll
                for (int tj = 0; tj < 4; ++tj) {
                    acc0[ti][tj] = __builtin_amdgcn_mfma_f32_16x16x32_bf16(
                        af[ti], b0[tj], acc0[ti][tj], 0, 0, 0);
                    acc1[ti][tj] = __builtin_amdgcn_mfma_f32_16x16x32_bf16(
                        af[ti], b1[tj], acc1[ti][tj], 0, 0, 0);
                }
        }
        __syncthreads();
    }

    u16* C0 = (u16*)((char*)C + (size_t)z0 * sCb);
    u16* C1 = (u16*)((char*)C + (size_t)(z0 + 1) * sCb);
    #pragma unroll
    for (int ti = 0; ti < 4; ++ti)
        #pragma unroll
        for (int tj = 0; tj < 4; ++tj) {
            const int nn = n0 + wn + tj * 16 + lrow;
            #pragma unroll
            for (int r2 = 0; r2 < 4; ++r2) {
                const int mm = m0 + wm + ti * 16 + quad * 4 + r2;
                C0[(size_t)mm * N + nn] = f2bf(acc0[ti][tj][r2]);
                C1[(size_t)mm * N + nn] = f2bf(acc1[ti][tj][r2]);
            }
        }
}

// ---------------- final GEMM (2-term): C_f32 = (Ah+Al) @ B(bf16,NxK)^T.
// Batched; strides in BYTES.
__global__ __launch_bounds__(256) void gemm_fin(
    const u16* __restrict__ Ah, const u16* __restrict__ Al,
    const u16* __restrict__ B, float* __restrict__ C,
    int M, int N, int K, size_t sAb, size_t sBb, size_t sCb)
{
    __shared__ u16 Ash[TM * BK];
    __shared__ u16 Asl[TM * BK];
    __shared__ u16 Bs[TN * BK];

    const int z = blockIdx.z;
    const u16* Ahb = (const u16*)((const char*)Ah + (size_t)z * sAb);
    const u16* Alb = (const u16*)((const char*)Al + (size_t)z * sAb);
    const u16* Bb  = (const u16*)((const char*)B + (size_t)z * sBb);

    const int n0 = blockIdx.x * TN;
    const int m0 = blockIdx.y * TM;
    const int tid = threadIdx.x;
    const int lane = tid & 63;
    const int wave = tid >> 6;
    const int wm = (wave >> 1) * 64;
    const int wn = (wave & 1) * 64;
    const int quad = lane >> 4;
    const int lrow = lane & 15;

    f32x4 acc[4][4] = {};

    for (int k0 = 0; k0 < K; k0 += BK) {
        #pragma unroll
        for (int r = 0; r < 4; ++r) {
            const int wbase = r * 4096 + wave * 1024;
            const int o = wbase + lane * 16;
            const int row = o >> 7;
            const int ce = (o & 127) >> 1;
            const size_t ao = (size_t)(m0 + row) * K + k0 + ce;
            const size_t bo = (size_t)(n0 + row) * K + k0 + ce;
            gload_lds16(Ahb + ao, (char*)Ash + wbase);
            gload_lds16(Alb + ao, (char*)Asl + wbase);
            gload_lds16(Bb + bo, (char*)Bs + wbase);
        }
        __syncthreads();

        #pragma unroll
        for (int kk = 0; kk < BK; kk += 32) {
            bf16x8 ah[4], al[4], bfr[4];
            #pragma unroll
            for (int t = 0; t < 4; ++t) {
                const int ra = (wm + t * 16 + lrow) * BK + kk + quad * 8;
                ah[t] = *(const bf16x8*)&Ash[ra];
                al[t] = *(const bf16x8*)&Asl[ra];
                bfr[t] = *(const bf16x8*)&Bs[(wn + t * 16 + lrow) * BK + kk + quad * 8];
            }
            #pragma unroll
            for (int ti = 0; ti < 4; ++ti)
                #pragma unroll
                for (int tj = 0; tj < 4; ++tj) {
                    acc[ti][tj] = __builtin_amdgcn_mfma_f32_16x16x32_bf16(
                        al[ti], bfr[tj], acc[ti][tj], 0, 0, 0);
                    acc[ti][tj] = __builtin_amdgcn_mfma_f32_16x16x32_bf16(
                        ah[ti], bfr[tj], acc[ti][tj], 0, 0, 0);
                }
        }
        __syncthreads();
    }

    float* Cb = (float*)((char*)C + (size_t)z * sCb);
    #pragma unroll
    for (int ti = 0; ti < 4; ++ti)
        #pragma unroll
        for (int tj = 0; tj < 4; ++tj) {
            const int nn = n0 + wn + tj * 16 + lrow;
            #pragma unroll
            for (int r2 = 0; r2 < 4; ++r2) {
                const int mm = m0 + wm + ti * 16 + quad * 4 + r2;
                Cb[(size_t)mm * N + nn] = acc[ti][tj][r2];
            }
        }
}

// Row softmax over Lh (8192 rows x 1024 fp32), diag (j == row%1024) -> -inf.
// Split-bf16 output.
__global__ __launch_bounds__(256) void softmax_split(
    const float* __restrict__ Lh, u16* __restrict__ Th, u16* __restrict__ Tl)
{
    const int lane = threadIdx.x & 63;
    const int wave = threadIdx.x >> 6;
    const size_t row = (size_t)blockIdx.x * 4 + wave;
    const int i = (int)(row & 1023);
    const float* src = Lh + row * 1024;
    const float NEG = -__builtin_inff();

    float v[16];
    float mx = NEG;
    #pragma unroll
    for (int cc = 0; cc < 4; ++cc) {
        f32x4 x = *(const f32x4*)(src + cc * 256 + lane * 4);
        #pragma unroll
        for (int e = 0; e < 4; ++e) {
            const int j = cc * 256 + lane * 4 + e;
            const float val = (j == i) ? NEG : x[e];
            v[cc * 4 + e] = val;
            mx = fmaxf(mx, val);
        }
    }
    #pragma unroll
    for (int off = 32; off > 0; off >>= 1) mx = fmaxf(mx, __shfl_xor(mx, off, 64));
    float s = 0.f;
    #pragma unroll
    for (int k = 0; k < 16; ++k) { v[k] = __expf(v[k] - mx); s += v[k]; }
    #pragma unroll
    for (int off = 32; off > 0; off >>= 1) s += __shfl_xor(s, off, 64);
    const float inv = 1.0f / s;

    #pragma unroll
    for (int cc = 0; cc < 4; ++cc) {
        u16x4 wh, wl;
        #pragma unroll
        for (int e = 0; e < 4; ++e) {
            BfPair p = split2(v[cc * 4 + e] * inv);
            wh[e] = p.h;
            wl[e] = p.l;
        }
        *(u16x4*)(Th + row * 1024 + cc * 256 + lane * 4) = wh;
        *(u16x4*)(Tl + row * 1024 + cc * 256 + lane * 4) = wl;
    }
}

// attn_f32[b][i][j] = (Th+Tl)[b][j][i]
__global__ __launch_bounds__(256) void transpose_attn_f32(
    const u16* __restrict__ Th, const u16* __restrict__ Tl, float* __restrict__ A)
{
    __shared__ float tile[64][65];
    const int bz = blockIdx.z;
    const int x0 = blockIdx.x * 64;
    const int y0 = blockIdx.y * 64;
    const size_t base = (size_t)bz * 1024 * 1024;
    float* dst = A + base;
    const int t = threadIdx.x;
    const int rt = t >> 4;
    const int c4 = (t & 15) * 4;

    #pragma unroll
    for (int p = 0; p < 4; ++p) {
        const int r = p * 16 + rt;
        const size_t off = base + (size_t)(y0 + r) * 1024 + x0 + c4;
        u16x4 vh = *(const u16x4*)(Th + off);
        u16x4 vl = *(const u16x4*)(Tl + off);
        #pragma unroll
        for (int e = 0; e < 4; ++e) tile[r][c4 + e] = bf2f(vh[e]) + bf2f(vl[e]);
    }
    __syncthreads();
    #pragma unroll
    for (int p = 0; p < 4; ++p) {
        const int a = p * 16 + rt;
        f32x4 w;
        #pragma unroll
        for (int e = 0; e < 4; ++e) w[e] = tile[c4 + e][a];
        *(f32x4*)(dst + (size_t)(x0 + a) * 1024 + y0 + c4) = w;
    }
}

extern "C" void kernel_launch(void* const* d_in, const int* in_sizes, int n_in,
                              void* d_out, int out_size, void* d_ws, size_t ws_size,
                              hipStream_t stream) {
    const float* y  = (const float*)d_in[0];   // (8,1024,2048) fp32
    const float* Wk = (const float*)d_in[1];   // (2048,2048)
    const float* Wq = (const float*)d_in[2];
    const float* Wv = (const float*)d_in[3];
    const float* Wo = (const float*)d_in[4];

    const int b = 8, n = 1024, d = 2048;
    const int MB = b * n;                 // 8192
    const size_t MiB = 1024 * 1024;

    // ===== Algebra:
    //   Gt[d',dd] = 0.1 * sum_e Wk[e,d']*Wq[e,dd]
    //   Zc[i,d']  = sum_dd yB[i,dd]*Gt[d',dd]               (2-term, Gt split)
    //   Lt[b,m,n] = sum_d' y_b[m,d']*Zc[b,n,d'] = K_m.Q_n   (2-term, Zc split)
    //   Ut[e,dd]  = sum_d Wo[e,d]*Wv[d,dd]
    //   VOt[b,e,j]= sum_dd Ut[e,dd]*y_b[j,dd]               (batch-paired 1-term)
    //   out[b,i,e]= sum_j (Th+Tl)[b,i,j]*VOt[b,e,j]
    // ===== Buffer liveness (sequential stream; no same-kernel in/out alias):
    // ws (128 MiB):
    //   [0,32)   yB ; [32,40) WkT |[40,48) WqT |[48,56) WvT |[56,64) WoB (dead after pre)
    //   [64,72)  GtH |[72,80) GtL (dead after Zc) ; [80,88) UtB (live till VOt)
    //   [32,64)  ZcH (over W's) ; [88,120) ZcL           (dead after Lt)
    //   [32,48)  Th / [48,64) Tl (over ZcH) ; [88,120) VOt (over ZcL)
    // d_out (96 MiB): [0,32) Lh (dead after softmax) -> outF [0,64) ; [64,96) attF
    char* ws = (char*)d_ws;
    u16* yB  = (u16*)(ws);
    u16* WkT = (u16*)(ws + 32 * MiB);
    u16* WqT = (u16*)(ws + 40 * MiB);
    u16* WvT = (u16*)(ws + 48 * MiB);
    u16* WoB = (u16*)(ws + 56 * MiB);
    u16* GtH = (u16*)(ws + 64 * MiB);
    u16* GtL = (u16*)(ws + 72 * MiB);
    u16* UtB = (u16*)(ws + 80 * MiB);
    u16* ZcH = (u16*)(ws + 32 * MiB);   // over WkT..WoB (dead)
    u16* ZcL = (u16*)(ws + 88 * MiB);
    u16* Th  = (u16*)(ws + 32 * MiB);   // over ZcH (dead after Lt)
    u16* Tl  = (u16*)(ws + 48 * MiB);
    u16* VOt = (u16*)(ws + 88 * MiB);   // over ZcL (dead after Lt)

    float* outF = (float*)d_out;                       // [0,64) final
    float* attF = outF + (size_t)MB * d;               // [64,96) final
    float* Lh   = (float*)d_out;                       // [0,32), dead before outF

    dim3 blk(256);
    // 1) y -> bf16; Wo -> bf16; Wk/Wq/Wv -> transposed bf16
    conv_bf<<<dim3(2048), blk, 0, stream>>>(y,  yB,  (MB * d) / 8);
    conv_bf<<<dim3(512),  blk, 0, stream>>>(Wo, WoB, (d * d) / 8);
    transpose3<<<dim3(32, 32, 3), blk, 0, stream>>>(Wk, Wq, Wv, WkT, WqT, WvT);
    // 2) merged: Gt = 0.1*WkT@WqT^T -> split AND Ut = WoB@WvT^T -> single
    gemm_pre<<<dim3(d / TN, d / TM, 1), blk, 0, stream>>>(
        WkT, WqT, GtH, GtL, 0.1f, WoB, WvT, UtB, d, d);
    // 3) Zc = yB @ Gt^T (2-term) -> split   (ZcH over dead W region)
    gemm_bs<true><<<dim3(d / TN, MB / TM, 1), blk, 0, stream>>>(
        yB, GtH, GtL, ZcH, ZcL, MB, d, d, 0, 0, 0);
    // 4) Lt[b,m,n] = sum_d' y_b[m,d']*Zc_b[n,d'] (2-term) -> fp32
    gemm_bs<false><<<dim3(n / TN, n / TM, b), blk, 0, stream>>>(
        yB, ZcH, ZcL, Lh, nullptr, n, n, d,
        (size_t)n * d * 2, (size_t)n * d * 2, (size_t)n * n * 4);
    // 5) T = row_softmax(Lt, diag) -> split (Th/Tl over ZcH; dead)
    softmax_split<<<dim3(MB / 4), blk, 0, stream>>>(Lh, Th, Tl);
    // 6) attn = (Th+Tl)^T as fp32 (Lh dead after)
    transpose_attn_f32<<<dim3(16, 16, b), blk, 0, stream>>>(Th, Tl, attF);
    // 7) VOt[b,e,j] = sum_dd Ut[e,dd]*y_b[j,dd] -> bf16 (batch-paired; over ZcL; dead)
    gemm_vo<<<dim3(n / TN, d / TM, b / 2), blk, 0, stream>>>(
        UtB, yB, VOt, d, n, d, (size_t)n * d * 2, (size_t)d * n * 2);
    // 8) out[b,i,e] = sum_j (Th+Tl)[b,i,j]*VOt[b,e,j] -> fp32 (Lh dead)
    gemm_fin<<<dim3(d / TN, n / TM, b), blk, 0, stream>>>(
        Th, Tl, VOt, outF, n, d, n,
        (size_t)n * n * 2, (size_t)d * n * 2, (size_t)n * d * 4);
}